// Round 10
// baseline (134.150 us; speedup 1.0000x reference)
//
#include <hip/hip_runtime.h>

// Problem constants (from reference)
#define T_TREES 200
#define BATCH   2048
#define D_FEAT  512
#define N_NODE  64
#define LR      0.01f

typedef __attribute__((__ext_vector_type__(8)))  __bf16 bf16x8;
typedef __attribute__((__ext_vector_type__(16))) float  f32x16;

__device__ __forceinline__ unsigned short f32_to_bf16(float f) {
    unsigned u = __float_as_uint(f);
    u += 0x7FFFu + ((u >> 16) & 1u);   // RNE
    return (unsigned short)(u >> 16);
}

__device__ __forceinline__ void gload_lds16(const void* g, void* l) {
    __builtin_amdgcn_global_load_lds(
        (__attribute__((address_space(1))) void*)(void*)g,
        (__attribute__((address_space(3))) void*)l,
        16, 0, 0);
}

// ---------------- fused prep kernel ----------------
// kg-major layouts so main-kernel access is contiguous:
// x_p[mt 16][kg 64][m 128][8k] bf16 ; w_p[pair 100][kg 64][n' 128][8k] bf16 ;
// w_dt[t 200][32 node][64 n] bf16.
// Grid 3456: [0,256) prep_x | [256,1856) prep_wt | [1856,3456) prep_wd.
__global__ __launch_bounds__(256) void prep_all(
    const float* __restrict__ x, const float* __restrict__ w_t,
    const float* __restrict__ w_d,
    unsigned short* __restrict__ x_p, unsigned short* __restrict__ w_p,
    unsigned short* __restrict__ w_dt) {
    __shared__ float tile[64 * 65];
    int b = blockIdx.x;
    if (b < 256) {
        // ---- x [2048][512] f32 -> x_p ----
        int mb = b >> 3, slab = b & 7;
        const float* src = x + (mb * 64) * D_FEAT + slab * 64;
        #pragma unroll
        for (int p = 0; p < 16; ++p) {
            int idx = p * 256 + threadIdx.x;
            int r = idx >> 6, c = idx & 63;
            tile[r * 65 + c] = src[r * D_FEAT + c];
        }
        __syncthreads();
        int mt = mb >> 1, mq = mb & 1;
        unsigned short* dst = x_p + mt * 65536 + slab * 8192 + mq * 512;
        #pragma unroll
        for (int p = 0; p < 8; ++p) {
            int idx = p * 256 + threadIdx.x;
            int kgl = idx >> 8;
            int r   = (idx >> 2) & 63;
            int jp  = idx & 3;
            ushort2 o;
            o.x = f32_to_bf16(tile[r * 65 + kgl * 8 + jp * 2]);
            o.y = f32_to_bf16(tile[r * 65 + kgl * 8 + jp * 2 + 1]);
            *(ushort2*)(dst + kgl * 1024 + r * 8 + jp * 2) = o;
        }
    } else if (b < 1856) {
        // ---- w_t [t][d][n] f32 -> w_p (pair-interleaved, kg-major) ----
        int bb = b - 256;
        int t = bb >> 3, slab = bb & 7;
        const float* src = w_t + t * (D_FEAT * N_NODE) + slab * 64 * N_NODE;
        #pragma unroll
        for (int p = 0; p < 16; ++p) {
            int idx = p * 256 + threadIdx.x;
            int d = idx >> 6, n = idx & 63;
            tile[d * 65 + n] = src[d * N_NODE + n];
        }
        __syncthreads();
        unsigned short* dst = w_p + (t >> 1) * 65536 + slab * 8192 + (t & 1) * 512;
        #pragma unroll
        for (int p = 0; p < 8; ++p) {
            int idx = p * 256 + threadIdx.x;
            int kgl = idx >> 8;
            int n   = (idx >> 2) & 63;
            int jp  = idx & 3;
            ushort2 o;
            o.x = f32_to_bf16(tile[(kgl * 8 + jp * 2) * 65 + n]);
            o.y = f32_to_bf16(tile[(kgl * 8 + jp * 2 + 1) * 65 + n]);
            *(ushort2*)(dst + kgl * 1024 + n * 8 + jp * 2) = o;
        }
    } else {
        // ---- w_d [t][n][15] f32 -> w_dt [t][32][64] (rows 15..31 zero) ----
        int i = (b - 1856) * 256 + threadIdx.x;          // 409600 = 200*32*64
        int n = i & 63;
        int l = (i >> 6) & 31;
        int t = i >> 11;
        float v = (l < 15) ? w_d[(t * 64 + n) * 15 + l] : 0.f;
        w_dt[i] = f32_to_bf16(v);
    }
}

// ---------------- main fused kernel ----------------
// Block = 1 tree x 512 batch rows, 256 threads (4 waves). Grid 800
// (8 XCD x 25 trees x 4 row-tiles). Wave tile 128m x 64n (4x2 = 8 acc chains).
// B (the tree's full weight, 64n x 512k = 64 KB) staged to LDS ONCE, one
// barrier, then the K-loop is BARRIER-FREE: B frags via fine-grained-lgkmcnt
// ds_read_b128, A frags register-direct from kg-major x_p (16 B/lane
// contiguous, 512 B half-wave runs, L2-resident) with a 2-step-deep software
// pipeline drained by fine-grained vmcnt — the structure the barrier-phased
// K-loop (R2-R9, pinned at 44-51 us = m97 plateau) cannot express.
// Regs ~185 unified (acc 128 AGPR + pipe 40 + addr) -> (256,2), no spill.
// LDS 69.6 KB (B 64K, H 512x68 bf16 overlay, P 512x17 f32) -> 2 blocks/CU.
__global__ __launch_bounds__(256, 2) void gbdt_main(
    const unsigned short* __restrict__ x_p,    // [16][64][128][8] bf16
    const unsigned short* __restrict__ w_p,    // [100][64][128][8] bf16
    const unsigned short* __restrict__ w_dt,   // [200][32][64] bf16
    const float* __restrict__ b_t,             // [200][64]
    const float* __restrict__ b_d,             // [200][15]
    const float* __restrict__ w_l,             // [200][16]
    const float* __restrict__ b_l,             // [200]
    float* __restrict__ f_ws)                  // [2048][200]  (b-major)
{
    // B: [0,65536) layout [kg 64][n 64][16B]. Overlays after GEMM1:
    // H [0,69632) = [512 m][68 col] bf16 (136 B stride: 2-way bank alias on
    // GEMM2 frag reads = free). P [0,34816) = [512][17] f32 (after GEMM2).
    __shared__ alignas(16) char smem[69632];
    unsigned short* Hs = (unsigned short*)smem;
    float*          Pf = (float*)smem;

    const int tid    = threadIdx.x;
    const int lane   = tid & 63;
    const int w      = tid >> 6;
    const int lane31 = lane & 31;
    const int kh     = lane >> 5;

    const int xcd  = blockIdx.x & 7;
    const int slot = blockIdx.x >> 3;     // 0..99
    const int t    = xcd * 25 + (slot >> 2);
    const int mt4  = slot & 3;            // 512-row tile
    const int m0   = mt4 * 512;

    // ---- stage B once: tree t's half of w_p pair, 64 KB, 16 issues/thread ----
    {
        const unsigned short* src =
            w_p + (t >> 1) * 65536 + (t & 1) * 512 + (w * 64 + lane31 * 2 + kh) * 8;
        // slot s = i*256 + tid: kg = i*4 + w (wave-uniform), r = lane
        #pragma unroll
        for (int i = 0; i < 16; ++i) {
            int kg = i * 4 + w;
            gload_lds16(w_p + (t >> 1) * 65536 + kg * 1024 + (t & 1) * 512 + lane * 8,
                        smem + kg * 1024 + lane * 16);
        }
        (void)src;
    }

    // A frag base (elems): frag(st, mb) = pA + (2*st+kh)*1024 + mb*256
    const unsigned short* pA =
        x_p + (mt4 * 4 + w) * 65536 + kh * 1024 + lane31 * 8;

    f32x16 acc[4][2];
    #pragma unroll
    for (int mb = 0; mb < 4; ++mb)
        #pragma unroll
        for (int nb = 0; nb < 2; ++nb)
            acc[mb][nb] = (f32x16)(0.f);

    // prologue: A steps 0 and 1 in flight
    bf16x8 a0[4], a1[4];
    #pragma unroll
    for (int mb = 0; mb < 4; ++mb) {
        a0[mb] = *(const bf16x8*)(pA + 0 * 2048 + mb * 256);
        a1[mb] = *(const bf16x8*)(pA + 1 * 2048 + mb * 256);
    }

    __syncthreads();                       // ONE barrier: B resident

    // ---- barrier-free K loop: 32 steps of k=16, unrolled by 2 ----
    #pragma unroll
    for (int c = 0; c < 16; ++c) {
        const int st0 = 2 * c, st1 = 2 * c + 1;
        bf16x8 n0[4], n1[4];
        #pragma unroll
        for (int mb = 0; mb < 4; ++mb) {
            n0[mb] = *(const bf16x8*)(pA + ((st0 + 2) & 31) * 2048 + mb * 256);
            n1[mb] = *(const bf16x8*)(pA + ((st1 + 2) & 31) * 2048 + mb * 256);
        }
        {
            bf16x8 bv[2];
            #pragma unroll
            for (int nb = 0; nb < 2; ++nb)
                bv[nb] = *(const bf16x8*)(smem + (2 * st0 + kh) * 1024 +
                                          (nb * 32 + lane31) * 16);
            #pragma unroll
            for (int mb = 0; mb < 4; ++mb)
                #pragma unroll
                for (int nb = 0; nb < 2; ++nb)
                    acc[mb][nb] = __builtin_amdgcn_mfma_f32_32x32x16_bf16(
                        a0[mb], bv[nb], acc[mb][nb], 0, 0, 0);
        }
        {
            bf16x8 bv[2];
            #pragma unroll
            for (int nb = 0; nb < 2; ++nb)
                bv[nb] = *(const bf16x8*)(smem + (2 * st1 + kh) * 1024 +
                                          (nb * 32 + lane31) * 16);
            #pragma unroll
            for (int mb = 0; mb < 4; ++mb)
                #pragma unroll
                for (int nb = 0; nb < 2; ++nb)
                    acc[mb][nb] = __builtin_amdgcn_mfma_f32_32x32x16_bf16(
                        a1[mb], bv[nb], acc[mb][nb], 0, 0, 0);
        }
        #pragma unroll
        for (int mb = 0; mb < 4; ++mb) { a0[mb] = n0[mb]; a1[mb] = n1[mb]; }
    }

    __syncthreads();                       // all B reads done; B region -> H

    // ---- epilogue: h = relu(acc + b_t) -> H LDS [512][68] bf16 ----
    // C/D layout (32x32): col = lane&31, row = (r&3) + 8*(r>>2) + 4*(lane>>5)
    #pragma unroll
    for (int nb = 0; nb < 2; ++nb) {
        float btv = b_t[t * 64 + nb * 32 + lane31];
        #pragma unroll
        for (int mb = 0; mb < 4; ++mb)
            #pragma unroll
            for (int r = 0; r < 16; ++r) {
                int m = w * 128 + mb * 32 + (r & 3) + 8 * (r >> 2) + 4 * kh;
                float h = fmaxf(acc[mb][nb][r] + btv, 0.f);
                Hs[m * 68 + nb * 32 + lane31] = f32_to_bf16(h);
            }
    }
    __syncthreads();                       // H complete

    // ---- GEMM2: logit[512 m x 16 l] = H @ w_dt[t]^T, K=64; acc dead ----
    f32x16 acc2[4];
    #pragma unroll
    for (int i = 0; i < 4; ++i) acc2[i] = (f32x16)(0.f);
    const unsigned short* pW = w_dt + t * 2048 + lane31 * 64 + kh * 8;
    #pragma unroll
    for (int s = 0; s < 4; ++s) {
        bf16x8 bv = *(const bf16x8*)(pW + s * 16);
        #pragma unroll
        for (int i = 0; i < 4; ++i) {
            bf16x8 av = *(const bf16x8*)(Hs + (w * 128 + i * 32 + lane31) * 68 +
                                         s * 16 + kh * 8);
            acc2[i] = __builtin_amdgcn_mfma_f32_32x32x16_bf16(av, bv, acc2[i], 0, 0, 0);
        }
    }
    __syncthreads();                       // H reads done (P overlays H)

    // ---- p = sigmoid(logit + b_d) -> P [512][17] f32 ----
    if (lane31 < 15) {
        float bdv = b_d[t * 15 + lane31];
        #pragma unroll
        for (int i = 0; i < 4; ++i)
            #pragma unroll
            for (int r = 0; r < 16; ++r) {
                int m = w * 128 + i * 32 + (r & 3) + 8 * (r >> 2) + 4 * kh;
                float lg = acc2[i][r] + bdv;
                Pf[m * 17 + lane31] = 1.f / (1.f + __expf(-lg));
            }
    }
    __syncthreads();

    // ---- soft routing + leaf score: thread = 2 rows ----
    #pragma unroll
    for (int h = 0; h < 2; ++h) {
        int m = h * 256 + tid;
        float pv[15];
        #pragma unroll
        for (int i = 0; i < 15; ++i) pv[i] = Pf[m * 17 + i];
        float facc = 0.f;
        #pragma unroll
        for (int leaf = 0; leaf < 16; ++leaf) {
            float mu = 1.f;
            int node = 0;
            #pragma unroll
            for (int d = 0; d < 4; ++d) {
                int bit = (leaf >> (3 - d)) & 1;
                float p = pv[node];
                mu *= bit ? (1.f - p) : p;
                node = 2 * node + 1 + bit;
            }
            facc += mu * w_l[t * 16 + leaf];
        }
        f_ws[(m0 + m) * T_TREES + t] = tanhf(facc + b_l[t]);   // b-major
    }
}

// ---------------- boosting prefix-sum ----------------
// f_ws is [B][T] -> coalesced read.
__global__ void scan_k(const float* __restrict__ f_ws, const float* __restrict__ f0p,
                       float* __restrict__ out) {
    int b = blockIdx.x, tid = threadIdx.x;
    int lane = tid & 63, wid = tid >> 6;
    float f0 = f0p[0];
    float x = (tid < T_TREES) ? f_ws[b * T_TREES + tid] : 0.f;
    #pragma unroll
    for (int off = 1; off < 64; off <<= 1) {
        float y = __shfl_up(x, off, 64);
        if (lane >= off) x += y;
    }
    __shared__ float wsum[4];
    if (lane == 63) wsum[wid] = x;
    __syncthreads();
    float base = 0.f;
    for (int i = 0; i < wid; ++i) base += wsum[i];
    float incl = x + base;
    if (tid == 0) out[b * (T_TREES + 1)] = f0;
    if (tid < T_TREES) out[b * (T_TREES + 1) + 1 + tid] = f0 + LR * incl;
}

extern "C" void kernel_launch(void* const* d_in, const int* in_sizes, int n_in,
                              void* d_out, int out_size, void* d_ws, size_t ws_size,
                              hipStream_t stream) {
    const float* x   = (const float*)d_in[0];
    const float* w_t = (const float*)d_in[2];
    const float* b_t = (const float*)d_in[3];
    const float* w_d = (const float*)d_in[4];
    const float* b_d = (const float*)d_in[5];
    const float* w_l = (const float*)d_in[6];
    const float* b_l = (const float*)d_in[7];
    const float* f_0 = (const float*)d_in[8];
    float* out = (float*)d_out;

    char* ws = (char*)d_ws;
    unsigned short* x_p  = (unsigned short*)(ws);               // 2,097,152 B
    unsigned short* w_p  = (unsigned short*)(ws + 2097152);     // 13,107,200 B
    unsigned short* w_dt = (unsigned short*)(ws + 15204352);    //   819,200 B
    float*          f_ws = (float*)(ws + 16023552);             // 1,638,400 B

    prep_all<<<3456, 256, 0, stream>>>(x, w_t, w_d, x_p, w_p, w_dt);
    gbdt_main<<<800, 256, 0, stream>>>(x_p, w_p, w_dt, b_t, b_d, w_l, b_l, f_ws);
    scan_k<<<BATCH, 256, 0, stream>>>(f_ws, f_0, out);
}